// Round 3
// baseline (71.781 us; speedup 1.0000x reference)
//
#include <hip/hip_runtime.h>

#define K   16          // tracked labels 1..16 (label 0 = background, never in loss)
#define NB  16          // batch
#define NP  409600      // 640*640 pixels per image
#define NPV (NP / 4)    // float4 vectors per image
#define BX  64          // blocks per image
#define NBLK (NB * BX)  // 1024 total blocks
#define SIGMA_DIS 3.0f

// Fused: per-(b,label) segment reduce -> partial table -> last block finalizes.
// ws layout (floats): [0..15] counter cacheline (uint at word 0),
//                     [16 ..)            ss_part [K][NBLK]   (transposed: contiguous per (k,b))
//                     [16+K*NBLK ..)     cnt_part[K][NBLK]
__global__ __launch_bounds__(256) void disc_loss_kernel(
    const float* __restrict__ pred,   // (NB, 4, NP)
    const int*   __restrict__ lab,    // (NB, NP)
    float* __restrict__ ws,
    float* __restrict__ out)
{
    const int tid  = threadIdx.x;
    const int lane = tid & 63;
    const int wave = tid >> 6;
    const int blk  = blockIdx.x;
    const int b    = blk >> 6;        // BX = 64
    const int bx   = blk & 63;

    float* ss_part  = ws + 16;
    float* cnt_part = ss_part + K * NBLK;
    unsigned int* counter = (unsigned int*)ws;

    float ssb[K];
    int   cnt[K];
#pragma unroll
    for (int k = 0; k < K; ++k) { ssb[k] = 0.0f; cnt[k] = 0; }

    const float4* p0 = (const float4*)(pred + ((size_t)b * 4 + 0) * NP);
    const float4* p1 = (const float4*)(pred + ((size_t)b * 4 + 1) * NP);
    const float4* p2 = (const float4*)(pred + ((size_t)b * 4 + 2) * NP);
    const float4* p3 = (const float4*)(pred + ((size_t)b * 4 + 3) * NP);
    const int4*   lb = (const int4*)(lab + (size_t)b * NP);

    for (int v = bx * 256 + tid; v < NPV; v += BX * 256) {
        float4 a = p0[v];
        float4 c = p1[v];
        float4 d = p2[v];
        float4 e = p3[v];
        int4   l = lb[v];

        float s0 = a.x * a.x + c.x * c.x + d.x * d.x + e.x * e.x;
        float s1 = a.y * a.y + c.y * c.y + d.y * d.y + e.y * e.y;
        float s2 = a.z * a.z + c.z * c.z + d.z * d.z + e.z * e.z;
        float s3 = a.w * a.w + c.w * c.w + d.w * d.w + e.w * e.w;

#pragma unroll
        for (int k = 0; k < K; ++k) {
            const int kk = k + 1;
            bool e0 = (l.x == kk);
            bool e1 = (l.y == kk);
            bool e2 = (l.z == kk);
            bool e3 = (l.w == kk);
            ssb[k] += e0 ? s0 : 0.0f;
            ssb[k] += e1 ? s1 : 0.0f;
            ssb[k] += e2 ? s2 : 0.0f;
            ssb[k] += e3 ? s3 : 0.0f;
            // wave-uniform counts on the scalar pipe; lane 0 always does the
            // max trip count (smallest v in wave), so its total is complete.
            cnt[k] += __popcll(__ballot(e0)) + __popcll(__ballot(e1))
                    + __popcll(__ballot(e2)) + __popcll(__ballot(e3));
        }
    }

    // --- wave reduce ss via register butterfly ---
#pragma unroll
    for (int k = 0; k < K; ++k) {
#pragma unroll
        for (int m = 1; m < 64; m <<= 1)
            ssb[k] += __shfl_xor(ssb[k], m, 64);
    }

    __shared__ float ss_sh[4][K];
    __shared__ int   cnt_sh[4][K];
    if (lane == 0) {
#pragma unroll
        for (int k = 0; k < K; ++k) { ss_sh[wave][k] = ssb[k]; cnt_sh[wave][k] = cnt[k]; }
    }
    __syncthreads();

    if (tid < K) {
        float s = ss_sh[0][tid] + ss_sh[1][tid] + ss_sh[2][tid] + ss_sh[3][tid];
        float c = (float)(cnt_sh[0][tid] + cnt_sh[1][tid] + cnt_sh[2][tid] + cnt_sh[3][tid]);
        ss_part [tid * NBLK + blk] = s;
        cnt_part[tid * NBLK + blk] = c;
    }
    __syncthreads();

    // --- ticket: last block to finish does the finalize ---
    __shared__ int is_last;
    if (tid == 0) {
        __threadfence();                          // release partial writes device-wide
        unsigned int old = atomicAdd(counter, 1u);
        is_last = (old == NBLK - 1) ? 1 : 0;
    }
    __syncthreads();
    if (!is_last) return;
    __threadfence();                              // acquire: see all blocks' partials

    // --- finalize (one block, coalesced float4 reads of the partial table) ---
    __shared__ float m_sh[NB][K];
    __shared__ float c_sh[NB][K];
    __shared__ float inv_denom[NB];
    __shared__ float red[256];

    {   // one (b,k) per thread; 256 threads cover NB*K exactly
        const int fb = tid >> 4;
        const int fk = tid & 15;
        const float4* sp = (const float4*)(ss_part  + fk * NBLK + fb * BX);
        const float4* cp = (const float4*)(cnt_part + fk * NBLK + fb * BX);
        float ss = 0.0f, cc = 0.0f;
#pragma unroll
        for (int i = 0; i < BX / 4; ++i) {
            float4 v = sp[i];
            float4 w = cp[i];
            ss += v.x + v.y + v.z + v.w;
            cc += w.x + w.y + w.z + w.w;
        }
        c_sh[fb][fk] = cc;
        m_sh[fb][fk] = (cc > 0.0f) ? ss / (cc * cc) : 0.0f;
    }
    __syncthreads();

    if (tid < NB) {
        int nk = 0;                               // max label value present (bins = labels 1..16)
        for (int k = K; k >= 1; --k) {
            if (c_sh[tid][k - 1] > 0.0f) { nk = k; break; }
        }
        float denom = (float)(nk * (nk - 1));
        inv_denom[tid] = (nk > 1) ? 1.0f / fmaxf(denom, 1.0f) : 0.0f;
    }
    __syncthreads();

    float acc = 0.0f;
    for (int e = tid; e < NB * K * K; e += 256) { // 4096 items, 16 iters
        const int fb = e >> 8;
        const int ij = e & 255;
        const int ki = ij >> 4;                   // label ki+1
        const int kj = ij & 15;                   // label kj+1
        if (kj > ki && c_sh[fb][ki] > 0.0f && c_sh[fb][kj] > 0.0f) {
            float s2 = m_sh[fb][ki] + m_sh[fb][kj];
            float dd = sqrtf(s2);
            float x  = SIGMA_DIS - dd;
            acc += log1pf(x * x) * inv_denom[fb];
        }
    }

    red[tid] = acc;
    __syncthreads();
    for (int s = 128; s > 0; s >>= 1) {
        if (tid < s) red[tid] += red[tid + s];
        __syncthreads();
    }
    if (tid == 0) out[0] = red[0];
}

extern "C" void kernel_launch(void* const* d_in, const int* in_sizes, int n_in,
                              void* d_out, int out_size, void* d_ws, size_t ws_size,
                              hipStream_t stream) {
    const float* pred = (const float*)d_in[0];
    const int*   lab  = (const int*)d_in[1];
    float* out = (float*)d_out;

    hipMemsetAsync(d_ws, 0, 64, stream);          // zero the ticket counter only
    disc_loss_kernel<<<NBLK, 256, 0, stream>>>(pred, lab, (float*)d_ws, out);
}

// Round 4
// 46.890 us; speedup vs baseline: 1.5309x; 1.5309x over previous
//
#include <hip/hip_runtime.h>

#define K   16          // tracked labels 1..16 (label 0 = background, never in loss)
#define NB  16          // batch
#define NP  409600      // 640*640 pixels per image
#define NPV (NP / 4)    // float4 vectors per image
#define BX  128         // blocks per image -> 2048 blocks = 8 blocks/CU = 32 waves/CU
#define NBLK (NB * BX)
#define SIGMA_DIS 3.0f

// ---------------- Stage 1: per-(b,label) sum of squared norms + counts ----------------
// Register bins (no atomics); counts on the scalar pipe via ballot+popcount;
// ss block-reduce via __shfl_xor butterfly + tiny LDS combine.
// Partial table transposed [k][blk] so stage 2 reads are coalesced float4.
__global__ __launch_bounds__(256, 8) void seg_reduce_kernel(
    const float* __restrict__ pred,   // (NB, 4, NP)
    const int*   __restrict__ lab,    // (NB, NP)
    float* __restrict__ ss_part,      // (K, NBLK)
    float* __restrict__ cnt_part)     // (K, NBLK)
{
    const int tid  = threadIdx.x;
    const int lane = tid & 63;
    const int wave = tid >> 6;
    const int b    = blockIdx.y;
    const int bx   = blockIdx.x;
    const int blk  = b * BX + bx;

    float ssb[K];
    int   cnt[K];
#pragma unroll
    for (int k = 0; k < K; ++k) { ssb[k] = 0.0f; cnt[k] = 0; }

    const float4* p0 = (const float4*)(pred + ((size_t)b * 4 + 0) * NP);
    const float4* p1 = (const float4*)(pred + ((size_t)b * 4 + 1) * NP);
    const float4* p2 = (const float4*)(pred + ((size_t)b * 4 + 2) * NP);
    const float4* p3 = (const float4*)(pred + ((size_t)b * 4 + 3) * NP);
    const int4*   lb = (const int4*)(lab + (size_t)b * NP);

    for (int v = bx * 256 + tid; v < NPV; v += BX * 256) {
        float4 a = p0[v];
        float4 c = p1[v];
        float4 d = p2[v];
        float4 e = p3[v];
        int4   l = lb[v];

        float s0 = a.x * a.x + c.x * c.x + d.x * d.x + e.x * e.x;
        float s1 = a.y * a.y + c.y * c.y + d.y * d.y + e.y * e.y;
        float s2 = a.z * a.z + c.z * c.z + d.z * d.z + e.z * e.z;
        float s3 = a.w * a.w + c.w * c.w + d.w * d.w + e.w * e.w;

#pragma unroll
        for (int k = 0; k < K; ++k) {
            const int kk = k + 1;
            bool e0 = (l.x == kk);
            bool e1 = (l.y == kk);
            bool e2 = (l.z == kk);
            bool e3 = (l.w == kk);
            ssb[k] += e0 ? s0 : 0.0f;
            ssb[k] += e1 ? s1 : 0.0f;
            ssb[k] += e2 ? s2 : 0.0f;
            ssb[k] += e3 ? s3 : 0.0f;
            // wave-uniform counts on the scalar pipe; lane 0 has the smallest v
            // in the wave, hence the max trip count, so its total is complete.
            cnt[k] += __popcll(__ballot(e0)) + __popcll(__ballot(e1))
                    + __popcll(__ballot(e2)) + __popcll(__ballot(e3));
        }
    }

    // --- wave reduce ss via register butterfly ---
#pragma unroll
    for (int k = 0; k < K; ++k) {
#pragma unroll
        for (int m = 1; m < 64; m <<= 1)
            ssb[k] += __shfl_xor(ssb[k], m, 64);
    }

    __shared__ float ss_sh[4][K];
    __shared__ int   cnt_sh[4][K];
    if (lane == 0) {
#pragma unroll
        for (int k = 0; k < K; ++k) { ss_sh[wave][k] = ssb[k]; cnt_sh[wave][k] = cnt[k]; }
    }
    __syncthreads();

    if (tid < K) {
        float s = ss_sh[0][tid] + ss_sh[1][tid] + ss_sh[2][tid] + ss_sh[3][tid];
        float c = (float)(cnt_sh[0][tid] + cnt_sh[1][tid] + cnt_sh[2][tid] + cnt_sh[3][tid]);
        ss_part [tid * NBLK + blk] = s;
        cnt_part[tid * NBLK + blk] = c;
    }
}

// ---------------- Stage 2: combine partials + pairwise loss ----------------
__global__ __launch_bounds__(256) void finalize_kernel(
    const float* __restrict__ ss_part,
    const float* __restrict__ cnt_part,
    float* __restrict__ out)
{
    __shared__ float m_sh[NB][K];
    __shared__ float c_sh[NB][K];
    __shared__ float inv_denom[NB];
    __shared__ float red[256];

    const int t = threadIdx.x;

    {   // one (b,k) per thread; 256 threads cover NB*K exactly; coalesced float4 rows
        const int fb = t >> 4;
        const int fk = t & 15;
        const float4* sp = (const float4*)(ss_part  + fk * NBLK + fb * BX);
        const float4* cp = (const float4*)(cnt_part + fk * NBLK + fb * BX);
        float ss = 0.0f, cc = 0.0f;
#pragma unroll
        for (int i = 0; i < BX / 4; ++i) {
            float4 v = sp[i];
            float4 w = cp[i];
            ss += v.x + v.y + v.z + v.w;
            cc += w.x + w.y + w.z + w.w;
        }
        c_sh[fb][fk] = cc;
        m_sh[fb][fk] = (cc > 0.0f) ? ss / (cc * cc) : 0.0f;
    }
    __syncthreads();

    if (t < NB) {
        int nk = 0;                               // max label value present (bins = labels 1..16)
        for (int k = K; k >= 1; --k) {
            if (c_sh[t][k - 1] > 0.0f) { nk = k; break; }
        }
        float denom = (float)(nk * (nk - 1));
        inv_denom[t] = (nk > 1) ? 1.0f / fmaxf(denom, 1.0f) : 0.0f;
    }
    __syncthreads();

    float acc = 0.0f;
    for (int e = t; e < NB * K * K; e += 256) {   // 4096 items, 16 iters
        const int fb = e >> 8;
        const int ij = e & 255;
        const int ki = ij >> 4;                   // label ki+1
        const int kj = ij & 15;                   // label kj+1
        if (kj > ki && c_sh[fb][ki] > 0.0f && c_sh[fb][kj] > 0.0f) {
            float s2 = m_sh[fb][ki] + m_sh[fb][kj];
            float dd = sqrtf(s2);
            float x  = SIGMA_DIS - dd;
            acc += log1pf(x * x) * inv_denom[fb];
        }
    }

    red[t] = acc;
    __syncthreads();
    for (int s = 128; s > 0; s >>= 1) {
        if (t < s) red[t] += red[t + s];
        __syncthreads();
    }
    if (t == 0) out[0] = red[0];
}

extern "C" void kernel_launch(void* const* d_in, const int* in_sizes, int n_in,
                              void* d_out, int out_size, void* d_ws, size_t ws_size,
                              hipStream_t stream) {
    const float* pred = (const float*)d_in[0];
    const int*   lab  = (const int*)d_in[1];
    float* out = (float*)d_out;

    float* ss_part  = (float*)d_ws;            // K*NBLK floats
    float* cnt_part = ss_part + K * NBLK;      // K*NBLK floats (256 KiB total, fully rewritten)

    dim3 grid(BX, NB);
    seg_reduce_kernel<<<grid, 256, 0, stream>>>(pred, lab, ss_part, cnt_part);
    finalize_kernel<<<1, 256, 0, stream>>>(ss_part, cnt_part, out);
}

// Round 5
// 41.442 us; speedup vs baseline: 1.7321x; 1.1315x over previous
//
#include <hip/hip_runtime.h>

#define K   16          // tracked labels 1..16 (label 0 = background, never in loss)
#define NB  16          // batch
#define NP  409600      // 640*640 pixels per image
#define NPV (NP / 4)    // float4 vectors per image
#define BX  64          // blocks per image -> 1024 blocks = exactly 4 blocks/CU
#define NBLK (NB * BX)
#define SIGMA_DIS 3.0f

// ---------------- Stage 1: per-(b,label) sum of squared norms + counts ----------------
// Per-lane privatized LDS histogram: bins[wave][label][lane] = (ss, cnt) float2.
// One ds_read_b64 + f2 add + ds_write_b64 per pixel; no atomics, no ballots,
// no big register arrays -> low VGPR, deep load pipelining.
__global__ __launch_bounds__(256) void seg_reduce_kernel(
    const float* __restrict__ pred,   // (NB, 4, NP)
    const int*   __restrict__ lab,    // (NB, NP)
    float* __restrict__ ss_part,      // (K, NBLK)  transposed for coalesced stage-2 reads
    float* __restrict__ cnt_part)     // (K, NBLK)
{
    __shared__ float2 bins[4][17][64];   // 34816 B
    __shared__ float2 red[16][16];       //  2048 B  -> 36864 B total: 4 blocks/CU

    const int tid  = threadIdx.x;
    const int lane = tid & 63;
    const int wave = tid >> 6;
    const int b    = blockIdx.y;
    const int bx   = blockIdx.x;
    const int blk  = b * BX + bx;

    for (int e = tid; e < 4 * 17 * 64; e += 256)
        ((float2*)bins)[e] = make_float2(0.0f, 0.0f);
    __syncthreads();

    float2* mybin = &bins[wave][0][lane];   // label k lives at mybin[k * 64]

    const float4* p0 = (const float4*)(pred + ((size_t)b * 4 + 0) * NP);
    const float4* p1 = (const float4*)(pred + ((size_t)b * 4 + 1) * NP);
    const float4* p2 = (const float4*)(pred + ((size_t)b * 4 + 2) * NP);
    const float4* p3 = (const float4*)(pred + ((size_t)b * 4 + 3) * NP);
    const int4*   lb = (const int4*)(lab + (size_t)b * NP);

#pragma unroll 2
    for (int v = bx * 256 + tid; v < NPV; v += BX * 256) {
        float4 a = p0[v];
        float4 c = p1[v];
        float4 d = p2[v];
        float4 e = p3[v];
        int4   l = lb[v];

        float s0 = a.x * a.x + c.x * c.x + d.x * d.x + e.x * e.x;
        float s1 = a.y * a.y + c.y * c.y + d.y * d.y + e.y * e.y;
        float s2 = a.z * a.z + c.z * c.z + d.z * d.z + e.z * e.z;
        float s3 = a.w * a.w + c.w * c.w + d.w * d.w + e.w * e.w;

        { float2 t = mybin[l.x * 64]; t.x += s0; t.y += 1.0f; mybin[l.x * 64] = t; }
        { float2 t = mybin[l.y * 64]; t.x += s1; t.y += 1.0f; mybin[l.y * 64] = t; }
        { float2 t = mybin[l.z * 64]; t.x += s2; t.y += 1.0f; mybin[l.z * 64] = t; }
        { float2 t = mybin[l.w * 64]; t.x += s3; t.y += 1.0f; mybin[l.w * 64] = t; }
    }
    __syncthreads();

    // --- block reduce: 256 slots (wave,lane) per label; 16 threads per label ---
    {
        const int rk = (tid & 15) + 1;    // label 1..16 (bin 0 = background, dropped)
        const int rs = tid >> 4;          // slot group 0..15
        float2 acc = make_float2(0.0f, 0.0f);
#pragma unroll
        for (int j = 0; j < 16; ++j) {
            const int slot = rs + j * 16;             // 0..255
            float2 t = bins[slot >> 6][rk][slot & 63];
            acc.x += t.x;
            acc.y += t.y;
        }
        red[tid & 15][rs] = acc;
    }
    __syncthreads();

    if (tid < 16) {
        float ss = 0.0f, cc = 0.0f;
#pragma unroll
        for (int s = 0; s < 16; ++s) { ss += red[tid][s].x; cc += red[tid][s].y; }
        ss_part [tid * NBLK + blk] = ss;
        cnt_part[tid * NBLK + blk] = cc;
    }
}

// ---------------- Stage 2: combine partials + pairwise loss ----------------
__global__ __launch_bounds__(256) void finalize_kernel(
    const float* __restrict__ ss_part,
    const float* __restrict__ cnt_part,
    float* __restrict__ out)
{
    __shared__ float m_sh[NB][K];
    __shared__ float c_sh[NB][K];
    __shared__ float inv_denom[NB];
    __shared__ float red[256];

    const int t = threadIdx.x;

    {   // one (b,k) per thread; 256 threads cover NB*K exactly; coalesced float4 rows
        const int fb = t >> 4;
        const int fk = t & 15;
        const float4* sp = (const float4*)(ss_part  + fk * NBLK + fb * BX);
        const float4* cp = (const float4*)(cnt_part + fk * NBLK + fb * BX);
        float ss = 0.0f, cc = 0.0f;
#pragma unroll
        for (int i = 0; i < BX / 4; ++i) {
            float4 v = sp[i];
            float4 w = cp[i];
            ss += v.x + v.y + v.z + v.w;
            cc += w.x + w.y + w.z + w.w;
        }
        c_sh[fb][fk] = cc;
        m_sh[fb][fk] = (cc > 0.0f) ? ss / (cc * cc) : 0.0f;
    }
    __syncthreads();

    if (t < NB) {
        int nk = 0;                               // max label value present (bins = labels 1..16)
        for (int k = K; k >= 1; --k) {
            if (c_sh[t][k - 1] > 0.0f) { nk = k; break; }
        }
        float denom = (float)(nk * (nk - 1));
        inv_denom[t] = (nk > 1) ? 1.0f / fmaxf(denom, 1.0f) : 0.0f;
    }
    __syncthreads();

    float acc = 0.0f;
    for (int e = t; e < NB * K * K; e += 256) {   // 4096 items, 16 iters
        const int fb = e >> 8;
        const int ij = e & 255;
        const int ki = ij >> 4;                   // label ki+1
        const int kj = ij & 15;                   // label kj+1
        if (kj > ki && c_sh[fb][ki] > 0.0f && c_sh[fb][kj] > 0.0f) {
            float s2 = m_sh[fb][ki] + m_sh[fb][kj];
            float dd = sqrtf(s2);
            float x  = SIGMA_DIS - dd;
            acc += log1pf(x * x) * inv_denom[fb];
        }
    }

    red[t] = acc;
    __syncthreads();
    for (int s = 128; s > 0; s >>= 1) {
        if (t < s) red[t] += red[t + s];
        __syncthreads();
    }
    if (t == 0) out[0] = red[0];
}

extern "C" void kernel_launch(void* const* d_in, const int* in_sizes, int n_in,
                              void* d_out, int out_size, void* d_ws, size_t ws_size,
                              hipStream_t stream) {
    const float* pred = (const float*)d_in[0];
    const int*   lab  = (const int*)d_in[1];
    float* out = (float*)d_out;

    float* ss_part  = (float*)d_ws;            // K*NBLK floats
    float* cnt_part = ss_part + K * NBLK;      // K*NBLK floats (128 KiB total, fully rewritten)

    dim3 grid(BX, NB);
    seg_reduce_kernel<<<grid, 256, 0, stream>>>(pred, lab, ss_part, cnt_part);
    finalize_kernel<<<1, 256, 0, stream>>>(ss_part, cnt_part, out);
}